// Round 14
// baseline (60.669 us; speedup 1.0000x reference)
//
#include <hip/hip_runtime.h>
#include <hip/hip_bf16.h>
#include <stdint.h>

#define VPn 8
#define BBn 2
#define CCn 512
#define NHn 8
#define HDn 64
#define Tn  2048
#define Mn  4096      // BBn*Tn
#define N1n 1536
#define Kn  512
#define QSC 0.180336880111120425f   // 0.125 * log2(e): softmax in exp2 domain

typedef __attribute__((ext_vector_type(8))) short bf16x8;
typedef __attribute__((ext_vector_type(4))) short s16x4;
typedef __attribute__((ext_vector_type(4))) float f32x4;
typedef __attribute__((ext_vector_type(16))) float f32x16;
typedef __attribute__((ext_vector_type(2))) unsigned int u32x2;
typedef unsigned short u16;
typedef unsigned int   u32;

__device__ __forceinline__ u16 f2bf(float f) {
  return __builtin_bit_cast(u16, __float2bfloat16(f));
}
// packed RNE f32x2 -> bf16x2 (same rounding as __float2bfloat16, 1 instr for 2 values)
__device__ __forceinline__ u32 cvtpk(float lo, float hi) {
  u32 r;
  asm("v_cvt_pk_bf16_f32 %0, %1, %2" : "=v"(r) : "v"(lo), "v"(hi));
  return r;
}
__device__ __forceinline__ void gload16(const void* g, void* l) {
  __builtin_amdgcn_global_load_lds(
      (const __attribute__((address_space(1))) u32*)g,
      (__attribute__((address_space(3))) u32*)l, 16, 0, 0);
}

// ---------- merged prologue: x transpose-convert + both W transposes ----------
__global__ __launch_bounds__(256) void prep(const float* __restrict__ x,
                                            const float* __restrict__ Wqkv,
                                            const float* __restrict__ Wo,
                                            u16* __restrict__ A,
                                            u16* __restrict__ WqkvT,
                                            u16* __restrict__ WoT) {
  int bi = blockIdx.x;   // 0..511 x ; 512..703 Wqkv ; 704..767 Wo
  __shared__ float t[64][65];
  int tid = threadIdx.x, col = tid & 63, r4 = tid >> 6;
  if (bi < 512) {
    int vb = bi >> 5;
    int ct = (bi >> 2) & 7;
    int ht = bi & 3;
    int v = vb >> 1, b = vb & 1;
    const float* src = x + ((size_t)vb * CCn + ct * 64) * 256 + ht * 64;
#pragma unroll
    for (int i = 0; i < 16; ++i) {
      int row = i * 4 + r4;                 // c within tile
      t[row][col] = src[row * 256 + col];   // col = hw within tile
    }
    __syncthreads();
    u16* dst = A + ((size_t)(b * Tn + v * 256 + ht * 64)) * Kn + ct * 64;
#pragma unroll
    for (int i = 0; i < 16; ++i) {
      int row = i * 4 + r4;                 // hw within tile
      dst[row * Kn + col] = f2bf(t[col][row]);
    }
  } else {
    const float* Win; u16* Wt; int Cc, rt, ct;
    if (bi < 704) { int k = bi - 512; Win = Wqkv; Wt = WqkvT; Cc = N1n; rt = k / 24; ct = k % 24; }
    else          { int k = bi - 704; Win = Wo;   Wt = WoT;   Cc = CCn; rt = k / 8;  ct = k % 8;  }
    const float* src = Win + (size_t)(rt * 64) * Cc + ct * 64;
#pragma unroll
    for (int i = 0; i < 16; ++i) {
      int row = i * 4 + r4;
      t[row][col] = src[row * Cc + col];
    }
    __syncthreads();
    u16* dst = Wt + (size_t)(ct * 64) * Kn + rt * 64;
#pragma unroll
    for (int i = 0; i < 16; ++i) {
      int row = i * 4 + r4;
      dst[row * Kn + col] = f2bf(t[col][row]);
    }
  }
}

// K' layout: [bh][kt][c][hi][lq][j]  (u16), flat = bh*131072 + kt*2048 + c*512 + hi*256 + lq*8 + j
// V' layout: [bh][kt][dh][ks][lq][pos] (u16), flat = bh*131072 + kt*2048 + dh*1024 + ks*512 + lq*16 + pos

// ---------- GEMM1: A x WqkvT -> Q (scaled), K', V'; 2-phase double-buffered staging ----------
__global__ __launch_bounds__(256, 3) void gemm_qkv(
    const u16* __restrict__ A, const u16* __restrict__ Bt, const float* __restrict__ bias,
    u16* __restrict__ Qo, u16* __restrict__ Kp, u16* __restrict__ Vp) {
  const int nt = N1n / 128;  // 12
  int m0 = (blockIdx.x / nt) * 64;
  int n0 = (blockIdx.x % nt) * 128;
  __shared__ __align__(16) u16 As[2][64 * 64];
  __shared__ __align__(16) u16 Bs[2][128 * 64];
  int tid = threadIdx.x, lane = tid & 63, w = tid >> 6;
  int wr = w & 1, wc = w >> 1;
  int li = lane & 15, g = lane >> 4;
  int rsub = lane >> 3, slot = lane & 7;
  int srcslot = slot ^ rsub;  // pre-swizzled global source (LDS dest stays linear)
  f32x4 acc[2][4] = {};

#define QKV_STAGE(buf, kk0)                                                    \
  {                                                                            \
    _Pragma("unroll")                                                          \
    for (int i = 0; i < 2; ++i) {                                              \
      int ci = w * 2 + i;                                                      \
      int row = ci * 8 + rsub;                                                 \
      gload16(A + (size_t)(m0 + row) * Kn + (kk0) + srcslot * 8,               \
              (char*)&As[buf][0] + ci * 1024);                                 \
    }                                                                          \
    _Pragma("unroll")                                                          \
    for (int i = 0; i < 4; ++i) {                                              \
      int ci = w * 4 + i;                                                      \
      int row = ci * 8 + rsub;                                                 \
      gload16(Bt + (size_t)(n0 + row) * Kn + (kk0) + srcslot * 8,              \
              (char*)&Bs[buf][0] + ci * 1024);                                 \
    }                                                                          \
  }

  QKV_STAGE(0, 0);
#pragma unroll
  for (int step = 0; step < 8; ++step) {
    const int cur = step & 1;
    if (step < 7) {
      QKV_STAGE(cur ^ 1, (step + 1) * 64);
      asm volatile("s_waitcnt vmcnt(6)");   // 6 newest (next tile) may stay in flight
    } else {
      asm volatile("s_waitcnt vmcnt(0)");
    }
    __builtin_amdgcn_s_barrier();
#pragma unroll
    for (int kk = 0; kk < 2; ++kk) {
      bf16x8 af[2], bfr[4];
#pragma unroll
      for (int mi = 0; mi < 2; ++mi) {
        int row = wr * 32 + mi * 16 + li;
        int sw = ((kk * 4 + g) ^ (row & 7)) * 8;
        af[mi] = *(const bf16x8*)(&As[cur][0] + row * 64 + sw);
      }
#pragma unroll
      for (int ni = 0; ni < 4; ++ni) {
        int row = wc * 64 + ni * 16 + li;
        int sw = ((kk * 4 + g) ^ (row & 7)) * 8;
        bfr[ni] = *(const bf16x8*)(&Bs[cur][0] + row * 64 + sw);
      }
#pragma unroll
      for (int mi = 0; mi < 2; ++mi)
#pragma unroll
        for (int ni = 0; ni < 4; ++ni)
          acc[mi][ni] = __builtin_amdgcn_mfma_f32_16x16x32_bf16(af[mi], bfr[ni], acc[mi][ni], 0, 0, 0);
    }
    asm volatile("s_waitcnt lgkmcnt(0)");
    __builtin_amdgcn_sched_barrier(0);
    __builtin_amdgcn_s_barrier();
  }
#pragma unroll
  for (int ni = 0; ni < 4; ++ni) {
    int n = n0 + wc * 64 + ni * 16 + li;
    float bn = bias[n];
    int sel = n >> 9, c = n & 511, hh = c >> 6, d = c & 63;
    if (sel == 0) {        // Q: [bh][t][d], scaled
#pragma unroll
      for (int mi = 0; mi < 2; ++mi) {
#pragma unroll
        for (int r = 0; r < 4; ++r) {
          int m = m0 + wr * 32 + mi * 16 + g * 4 + r;
          int bq = m >> 11, t = m & 2047;
          Qo[((size_t)((bq * NHn + hh) * Tn + t)) * HDn + d] = f2bf((acc[mi][ni][r] + bn) * QSC);
        }
      }
    } else if (sel == 1) {  // K': tiled fragment layout
      int kc = d >> 4, khi = (d >> 3) & 1, kj = d & 7;
#pragma unroll
      for (int mi = 0; mi < 2; ++mi) {
#pragma unroll
        for (int r = 0; r < 4; ++r) {
          int m = m0 + wr * 32 + mi * 16 + g * 4 + r;
          int bq = m >> 11, t = m & 2047;
          size_t off = (size_t)(bq * NHn + hh) * 131072 + (size_t)(t >> 5) * 2048 +
                       kc * 512 + khi * 256 + (t & 31) * 8 + kj;
          Kp[off] = f2bf(acc[mi][ni][r] + bn);
        }
      }
    } else {                // V': tiled slot layout, 4 consecutive keys pack to 8B
      int dh = d >> 5, lqd = d & 31;
#pragma unroll
      for (int mi = 0; mi < 2; ++mi) {
        int mb = m0 + wr * 32 + mi * 16 + g * 4;
        int bq = mb >> 11, t0 = mb & 2047;
        size_t off = (size_t)(bq * NHn + hh) * 131072 + (size_t)(t0 >> 5) * 2048 +
                     dh * 1024 + ((t0 >> 4) & 1) * 512 + lqd * 16 +
                     ((t0 >> 2) & 1) * 8 + ((t0 >> 3) & 1) * 4;
        u32x2 ov;
        ov.x = cvtpk(acc[mi][ni][0] + bn, acc[mi][ni][1] + bn);
        ov.y = cvtpk(acc[mi][ni][2] + bn, acc[mi][ni][3] + bn);
        *(u32x2*)(Vp + off) = ov;
      }
    }
  }
}

// ---------- flash attention, block-causal, 32x32 swapped MFMA ----------
// Block (512 thr, 8 waves) = one 64-q-row pair x one bh. Wave w: segment w>>1, q-tile w&1.
// K/V tiles staged cooperatively into LDS (async gload_lds, double-buffered): each tile is
// fetched from L2 ONCE per q-pair (was twice) — halves attn's L2 K/V traffic.
// Per-wave math path identical to the verified round-10 single-tile code.
// XCD-pinned: bh = (idx&7)|((idx>>3)&1)<<3 keeps 2 bh per XCD (1MB K+V in local L2).
__global__ __launch_bounds__(512, 4) void attn(
    const u16* __restrict__ Q, const u16* __restrict__ Kp, const u16* __restrict__ Vp,
    u16* __restrict__ Y) {
  int idx = blockIdx.x;            // 512 = 32 qp * 16 bh
  int bh = (idx & 7) | (((idx >> 3) & 1) << 3);
  int qp = 31 - (idx >> 4);        // heavy first
  int b = bh >> 3, h = bh & 7;
  int nkeys = ((qp >> 2) + 1) << 8;   // same for q-tiles 2qp and 2qp+1
  int ntile = nkeys >> 7;          // 32-key tiles per segment (nkeys/4/32), >= 2
  int tid = threadIdx.x;
  int w = tid >> 6;
  int seg = w >> 1, jt = w & 1;
  int tile0 = seg * ntile;
  int lane = tid & 63;
  int lq = lane & 31, hi = lane >> 5;

  const u16* Qb = Q + ((size_t)(bh * Tn + (qp << 6) + jt * 32)) * HDn;
  const u16* Kb = Kp + (size_t)bh * 131072;
  const u16* Vb = Vp + (size_t)bh * 131072;
  const u16* sbase = (w & 1) ? Vb : Kb;  // even waves stage K, odd stage V (own segment)
  int kof = hi * 256 + lq * 8;     // K lane offset within 2048-u16 tile
  int vof = lq * 16 + hi * 8;      // V lane offset within 2048-u16 tile

  // LDS: staging [buf][K/V][seg][2048 u16] = 64KB, overlaid later by combine arrays (71.7KB)
  __shared__ __align__(16) char smem[71680];
  u16 (*KVs)[2][4][2048] = (u16 (*)[2][4][2048])smem;

  // Q^T B-frags: chunk c holds B[d=c*16+hi*8+j][q=lq]
  bf16x8 qf[4];
  {
    const u16* qptr = Qb + (size_t)lq * HDn + hi * 8;
#pragma unroll
    for (int c = 0; c < 4; ++c) qf[c] = *(const bf16x8*)(qptr + c * 16);
  }

  float mrun = -1e30f, lrun = 0.f;   // per-lane partials
  f32x16 oacc0 = {}, oacc1 = {};     // O^T d=0-31 / 32-63, col q=lq

#define AST(buf, t)                                                            \
  {                                                                            \
    _Pragma("unroll")                                                          \
    for (int i_ = 0; i_ < 4; ++i_)                                             \
      gload16(sbase + (size_t)(tile0 + (t)) * 2048 + i_ * 512 + lane * 8,      \
              &KVs[buf][w & 1][seg][i_ * 512]);                                \
  }

  AST(0, 0);
  asm volatile("s_waitcnt vmcnt(0)");
  __builtin_amdgcn_s_barrier();

  for (int t = 0; t < ntile; ++t) {
    const int cur = t & 1;
    if (t + 1 < ntile) { AST(cur ^ 1, t + 1); }
    bf16x8 kc[4], vc[4];
#pragma unroll
    for (int c = 0; c < 4; ++c) {
      kc[c] = *(const bf16x8*)&KVs[cur][0][seg][c * 512 + kof];
      vc[c] = *(const bf16x8*)&KVs[cur][1][seg][c * 512 + vof];
    }
    // S^T[key][q] in exp2 units: col=q=lq, row=key=(r&3)+8*(r>>2)+4*hi
    f32x16 s = {};
    __builtin_amdgcn_s_setprio(1);
#pragma unroll
    for (int c = 0; c < 4; ++c)
      s = __builtin_amdgcn_mfma_f32_32x32x16_bf16(kc[c], qf[c], s, 0, 0, 0);
    __builtin_amdgcn_s_setprio(0);

    float m0_ = fmaxf(fmaxf(fmaxf(fmaxf(s[0], s[1]), fmaxf(s[2], s[3])),
                            fmaxf(fmaxf(s[4], s[5]), fmaxf(s[6], s[7]))),
                      fmaxf(fmaxf(fmaxf(s[8], s[9]), fmaxf(s[10], s[11])),
                            fmaxf(fmaxf(s[12], s[13]), fmaxf(s[14], s[15]))));
    float mall = fmaxf(m0_, __shfl_xor(m0_, 32));
    if (!__all(mall <= mrun + 8.0f)) {
      float mnew = fmaxf(mrun, mall);
      float fc = exp2f(mrun - mnew);
      mrun = mnew;
      lrun *= fc;
#pragma unroll
      for (int j = 0; j < 16; ++j) { oacc0[j] *= fc; oacc1[j] *= fc; }
    }
    float p[16];
#pragma unroll
    for (int j = 0; j < 16; ++j) p[j] = exp2f(s[j] - mrun);
    lrun += (((p[0] + p[1]) + (p[2] + p[3])) + ((p[4] + p[5]) + (p[6] + p[7]))) +
            (((p[8] + p[9]) + (p[10] + p[11])) + ((p[12] + p[13]) + (p[14] + p[15])));
    bf16x8 pfA, pfB;
    {
      __attribute__((ext_vector_type(4))) int pa_ = {
          (int)cvtpk(p[0], p[1]), (int)cvtpk(p[2], p[3]),
          (int)cvtpk(p[4], p[5]), (int)cvtpk(p[6], p[7])};
      __attribute__((ext_vector_type(4))) int pb_ = {
          (int)cvtpk(p[8], p[9]), (int)cvtpk(p[10], p[11]),
          (int)cvtpk(p[12], p[13]), (int)cvtpk(p[14], p[15])};
      pfA = __builtin_bit_cast(bf16x8, pa_);
      pfB = __builtin_bit_cast(bf16x8, pb_);
    }
    __builtin_amdgcn_s_setprio(1);
    oacc0 = __builtin_amdgcn_mfma_f32_32x32x16_bf16(vc[0], pfA, oacc0, 0, 0, 0);
    oacc0 = __builtin_amdgcn_mfma_f32_32x32x16_bf16(vc[1], pfB, oacc0, 0, 0, 0);
    oacc1 = __builtin_amdgcn_mfma_f32_32x32x16_bf16(vc[2], pfA, oacc1, 0, 0, 0);
    oacc1 = __builtin_amdgcn_mfma_f32_32x32x16_bf16(vc[3], pfB, oacc1, 0, 0, 0);
    __builtin_amdgcn_s_setprio(0);

    asm volatile("s_waitcnt vmcnt(0)");   // next tile staged before barrier
    __builtin_amdgcn_s_barrier();
  }

  // total l per query column (cross-half)
  lrun += __shfl_xor(lrun, 32);

  __syncthreads();   // staging phase fully done -> safe to overlay combine arrays
  float* OlB = (float*)smem;             // [set][seg][32 q][68]
  float* mlB = (float*)(smem + 69632);   // [set][m/l][seg][32 q]
  {
    float* op = OlB + (size_t)((jt * 4 + seg) * 32 + lq) * 68 + hi * 4;
#pragma unroll
    for (int a = 0; a < 4; ++a) {
      f32x4 v0 = {oacc0[4 * a], oacc0[4 * a + 1], oacc0[4 * a + 2], oacc0[4 * a + 3]};
      f32x4 v1 = {oacc1[4 * a], oacc1[4 * a + 1], oacc1[4 * a + 2], oacc1[4 * a + 3]};
      *(f32x4*)(op + a * 8) = v0;
      *(f32x4*)(op + 32 + a * 8) = v1;
    }
    if (lane < 32) {
      mlB[((jt * 2 + 0) * 4 + seg) * 32 + lq] = mrun;
      mlB[((jt * 2 + 1) * 4 + seg) * 32 + lq] = lrun;
    }
  }
  __syncthreads();

  // in-block combine of 4 segments for both q-tiles; write Y bf16 [b][t][c]
  for (int task = tid; task < 1024; task += 512) {
    int set = task >> 9;
    int q = (task >> 4) & 31;
    int quad = task & 15;
    float m0v = mlB[((set * 2) * 4 + 0) * 32 + q];
    float m1v = mlB[((set * 2) * 4 + 1) * 32 + q];
    float m2v = mlB[((set * 2) * 4 + 2) * 32 + q];
    float m3v = mlB[((set * 2) * 4 + 3) * 32 + q];
    float mx = fmaxf(fmaxf(m0v, m1v), fmaxf(m2v, m3v));
    float w0 = exp2f(m0v - mx), w1 = exp2f(m1v - mx);
    float w2 = exp2f(m2v - mx), w3 = exp2f(m3v - mx);
    float l = mlB[((set * 2 + 1) * 4 + 0) * 32 + q] * w0 +
              mlB[((set * 2 + 1) * 4 + 1) * 32 + q] * w1 +
              mlB[((set * 2 + 1) * 4 + 2) * 32 + q] * w2 +
              mlB[((set * 2 + 1) * 4 + 3) * 32 + q] * w3;
    float inv = 1.0f / l;
    f32x4 o0 = *(const f32x4*)(OlB + (size_t)((set * 4 + 0) * 32 + q) * 68 + quad * 4);
    f32x4 o1 = *(const f32x4*)(OlB + (size_t)((set * 4 + 1) * 32 + q) * 68 + quad * 4);
    f32x4 o2 = *(const f32x4*)(OlB + (size_t)((set * 4 + 2) * 32 + q) * 68 + quad * 4);
    f32x4 o3 = *(const f32x4*)(OlB + (size_t)((set * 4 + 3) * 32 + q) * 68 + quad * 4);
    float y0 = (o0[0] * w0 + o1[0] * w1 + o2[0] * w2 + o3[0] * w3) * inv;
    float y1 = (o0[1] * w0 + o1[1] * w1 + o2[1] * w2 + o3[1] * w3) * inv;
    float y2 = (o0[2] * w0 + o1[2] * w1 + o2[2] * w2 + o3[2] * w3) * inv;
    float y3 = (o0[3] * w0 + o1[3] * w1 + o2[3] * w2 + o3[3] * w3) * inv;
    u32x2 yv;
    yv.x = cvtpk(y0, y1);
    yv.y = cvtpk(y2, y3);
    *(u32x2*)(Y + ((size_t)(b * Tn + (qp << 6) + set * 32 + q)) * CCn + h * HDn + quad * 4) = yv;
  }
}

// ---------- GEMM2: Y x WoT + bias -> out (v,b,c,h,w) f32, fused transpose; 2-phase staging ----------
__global__ __launch_bounds__(256, 4) void gemm_out(
    const u16* __restrict__ A, const u16* __restrict__ Bt, const float* __restrict__ bias,
    float* __restrict__ out) {
  const int nt = 8;
  int m0 = (blockIdx.x / nt) * 64;
  int n0 = (blockIdx.x % nt) * 64;
  __shared__ __align__(16) u16 As[2][64 * 64];
  __shared__ __align__(16) u16 Bs[2][64 * 64];
  int tid = threadIdx.x, lane = tid & 63, w = tid >> 6;
  int wr = w & 1, wc = w >> 1;
  int li = lane & 15, g = lane >> 4;
  int rsub = lane >> 3, slot = lane & 7;
  int srcslot = slot ^ rsub;
  f32x4 acc[2][2] = {};

#define OUT_STAGE(buf, kk0)                                                    \
  {                                                                            \
    _Pragma("unroll")                                                          \
    for (int i = 0; i < 2; ++i) {                                              \
      int ci = w * 2 + i;                                                      \
      int row = ci * 8 + rsub;                                                 \
      gload16(A + (size_t)(m0 + row) * Kn + (kk0) + srcslot * 8,               \
              (char*)&As[buf][0] + ci * 1024);                                 \
      gload16(Bt + (size_t)(n0 + row) * Kn + (kk0) + srcslot * 8,              \
              (char*)&Bs[buf][0] + ci * 1024);                                 \
    }                                                                          \
  }

  OUT_STAGE(0, 0);
#pragma unroll
  for (int step = 0; step < 8; ++step) {
    const int cur = step & 1;
    if (step < 7) {
      OUT_STAGE(cur ^ 1, (step + 1) * 64);
      asm volatile("s_waitcnt vmcnt(4)");
    } else {
      asm volatile("s_waitcnt vmcnt(0)");
    }
    __builtin_amdgcn_s_barrier();
#pragma unroll
    for (int kk = 0; kk < 2; ++kk) {
      bf16x8 af[2], bfr[2];
#pragma unroll
      for (int mi = 0; mi < 2; ++mi) {
        int row = wr * 32 + mi * 16 + li;
        int sw = ((kk * 4 + g) ^ (row & 7)) * 8;
        af[mi] = *(const bf16x8*)(&As[cur][0] + row * 64 + sw);
      }
#pragma unroll
      for (int ni = 0; ni < 2; ++ni) {
        int row = wc * 32 + ni * 16 + li;
        int sw = ((kk * 4 + g) ^ (row & 7)) * 8;
        bfr[ni] = *(const bf16x8*)(&Bs[cur][0] + row * 64 + sw);
      }
#pragma unroll
      for (int mi = 0; mi < 2; ++mi)
#pragma unroll
        for (int ni = 0; ni < 2; ++ni)
          acc[mi][ni] = __builtin_amdgcn_mfma_f32_16x16x32_bf16(af[mi], bfr[ni], acc[mi][ni], 0, 0, 0);
    }
    asm volatile("s_waitcnt lgkmcnt(0)");
    __builtin_amdgcn_sched_barrier(0);
    __builtin_amdgcn_s_barrier();
  }
  // epilogue: out[(v*2+b)*512 + n][hw], m = b*2048 + v*256 + hw; m0 64-aligned -> b,v fixed
  int b = m0 >> 11, v = (m0 >> 8) & 7, hw0 = m0 & 255;
  float* ob = out + (size_t)((v * 2 + b) * 512) * 256;
#pragma unroll
  for (int ni = 0; ni < 2; ++ni) {
    int n = n0 + wc * 32 + ni * 16 + li;
    float bn = bias[n];
#pragma unroll
    for (int mi = 0; mi < 2; ++mi) {
      int hw = hw0 + wr * 32 + mi * 16 + g * 4;
      f32x4 y;
#pragma unroll
      for (int r = 0; r < 4; ++r) y[r] = acc[mi][ni][r] + bn;
      *(f32x4*)(ob + (size_t)n * 256 + hw) = y;
    }
  }
}

extern "C" void kernel_launch(void* const* d_in, const int* in_sizes, int n_in,
                              void* d_out, int out_size, void* d_ws, size_t ws_size,
                              hipStream_t stream) {
  (void)in_sizes; (void)n_in; (void)out_size; (void)ws_size;
  const float* x    = (const float*)d_in[0];
  const float* Wqkv = (const float*)d_in[1];
  const float* bqkv = (const float*)d_in[2];
  const float* Wo   = (const float*)d_in[3];
  const float* bo   = (const float*)d_in[4];
  float* out = (float*)d_out;
  char* ws = (char*)d_ws;
  const size_t MB = 1ull << 20;
  u16*   Abf   = (u16*)(ws + 0);          // 4MB; reused as Y (bf16) after attn
  u16*   WqkvT = (u16*)(ws + 4 * MB);     // 1.5MB
  u16*   WoT   = (u16*)(ws + 5 * MB + 512 * 1024);  // 0.5MB
  u16*   Qb    = (u16*)(ws + 6 * MB);     // 4MB
  u16*   Kb    = (u16*)(ws + 10 * MB);    // 4MB (K' tiled)
  u16*   VTb   = (u16*)(ws + 14 * MB);    // 4MB (V' tiled)  -> peak 18MB

  prep<<<768, 256, 0, stream>>>(x, Wqkv, Wo, Abf, WqkvT, WoT);
  gemm_qkv<<<64 * 12, 256, 0, stream>>>(Abf, WqkvT, bqkv, Qb, Kb, VTb);
  attn<<<512, 512, 0, stream>>>(Qb, Kb, VTb, Abf);
  gemm_out<<<64 * 8, 256, 0, stream>>>(Abf, WoT, bo, out);
}

// Round 16
// 57.715 us; speedup vs baseline: 1.0512x; 1.0512x over previous
//
#include <hip/hip_runtime.h>
#include <hip/hip_bf16.h>
#include <stdint.h>

#define VPn 8
#define BBn 2
#define CCn 512
#define NHn 8
#define HDn 64
#define Tn  2048
#define Mn  4096      // BBn*Tn
#define N1n 1536
#define Kn  512
#define QSC 0.180336880111120425f   // 0.125 * log2(e): softmax in exp2 domain

typedef __attribute__((ext_vector_type(8))) short bf16x8;
typedef __attribute__((ext_vector_type(4))) short s16x4;
typedef __attribute__((ext_vector_type(4))) float f32x4;
typedef __attribute__((ext_vector_type(16))) float f32x16;
typedef __attribute__((ext_vector_type(2))) unsigned int u32x2;
typedef unsigned short u16;
typedef unsigned int   u32;

__device__ __forceinline__ u16 f2bf(float f) {
  return __builtin_bit_cast(u16, __float2bfloat16(f));
}
// packed RNE f32x2 -> bf16x2 (same rounding as __float2bfloat16, 1 instr for 2 values)
__device__ __forceinline__ u32 cvtpk(float lo, float hi) {
  u32 r;
  asm("v_cvt_pk_bf16_f32 %0, %1, %2" : "=v"(r) : "v"(lo), "v"(hi));
  return r;
}
__device__ __forceinline__ void gload16(const void* g, void* l) {
  __builtin_amdgcn_global_load_lds(
      (const __attribute__((address_space(1))) u32*)g,
      (__attribute__((address_space(3))) u32*)l, 16, 0, 0);
}

// ---------- merged prologue: x transpose-convert + both W transposes ----------
__global__ __launch_bounds__(256) void prep(const float* __restrict__ x,
                                            const float* __restrict__ Wqkv,
                                            const float* __restrict__ Wo,
                                            u16* __restrict__ A,
                                            u16* __restrict__ WqkvT,
                                            u16* __restrict__ WoT) {
  int bi = blockIdx.x;   // 0..511 x ; 512..703 Wqkv ; 704..767 Wo
  __shared__ float t[64][65];
  int tid = threadIdx.x, col = tid & 63, r4 = tid >> 6;
  if (bi < 512) {
    int vb = bi >> 5;
    int ct = (bi >> 2) & 7;
    int ht = bi & 3;
    int v = vb >> 1, b = vb & 1;
    const float* src = x + ((size_t)vb * CCn + ct * 64) * 256 + ht * 64;
#pragma unroll
    for (int i = 0; i < 16; ++i) {
      int row = i * 4 + r4;                 // c within tile
      t[row][col] = src[row * 256 + col];   // col = hw within tile
    }
    __syncthreads();
    u16* dst = A + ((size_t)(b * Tn + v * 256 + ht * 64)) * Kn + ct * 64;
#pragma unroll
    for (int i = 0; i < 16; ++i) {
      int row = i * 4 + r4;                 // hw within tile
      dst[row * Kn + col] = f2bf(t[col][row]);
    }
  } else {
    const float* Win; u16* Wt; int Cc, rt, ct;
    if (bi < 704) { int k = bi - 512; Win = Wqkv; Wt = WqkvT; Cc = N1n; rt = k / 24; ct = k % 24; }
    else          { int k = bi - 704; Win = Wo;   Wt = WoT;   Cc = CCn; rt = k / 8;  ct = k % 8;  }
    const float* src = Win + (size_t)(rt * 64) * Cc + ct * 64;
#pragma unroll
    for (int i = 0; i < 16; ++i) {
      int row = i * 4 + r4;
      t[row][col] = src[row * Cc + col];
    }
    __syncthreads();
    u16* dst = Wt + (size_t)(ct * 64) * Kn + rt * 64;
#pragma unroll
    for (int i = 0; i < 16; ++i) {
      int row = i * 4 + r4;
      dst[row * Kn + col] = f2bf(t[col][row]);
    }
  }
}

// K' layout: [bh][kt][c][hi][lq][j]  (u16), flat = bh*131072 + kt*2048 + c*512 + hi*256 + lq*8 + j
// V' layout: [bh][kt][dh][ks][lq][pos] (u16), flat = bh*131072 + kt*2048 + dh*1024 + ks*512 + lq*16 + pos

// ---------- GEMM1: A x WqkvT -> Q (scaled), K', V'; 2-phase double-buffered staging ----------
__global__ __launch_bounds__(256, 3) void gemm_qkv(
    const u16* __restrict__ A, const u16* __restrict__ Bt, const float* __restrict__ bias,
    u16* __restrict__ Qo, u16* __restrict__ Kp, u16* __restrict__ Vp) {
  const int nt = N1n / 128;  // 12
  int m0 = (blockIdx.x / nt) * 64;
  int n0 = (blockIdx.x % nt) * 128;
  __shared__ __align__(16) u16 As[2][64 * 64];
  __shared__ __align__(16) u16 Bs[2][128 * 64];
  int tid = threadIdx.x, lane = tid & 63, w = tid >> 6;
  int wr = w & 1, wc = w >> 1;
  int li = lane & 15, g = lane >> 4;
  int rsub = lane >> 3, slot = lane & 7;
  int srcslot = slot ^ rsub;  // pre-swizzled global source (LDS dest stays linear)
  f32x4 acc[2][4] = {};

#define QKV_STAGE(buf, kk0)                                                    \
  {                                                                            \
    _Pragma("unroll")                                                          \
    for (int i = 0; i < 2; ++i) {                                              \
      int ci = w * 2 + i;                                                      \
      int row = ci * 8 + rsub;                                                 \
      gload16(A + (size_t)(m0 + row) * Kn + (kk0) + srcslot * 8,               \
              (char*)&As[buf][0] + ci * 1024);                                 \
    }                                                                          \
    _Pragma("unroll")                                                          \
    for (int i = 0; i < 4; ++i) {                                              \
      int ci = w * 4 + i;                                                      \
      int row = ci * 8 + rsub;                                                 \
      gload16(Bt + (size_t)(n0 + row) * Kn + (kk0) + srcslot * 8,              \
              (char*)&Bs[buf][0] + ci * 1024);                                 \
    }                                                                          \
  }

  QKV_STAGE(0, 0);
#pragma unroll
  for (int step = 0; step < 8; ++step) {
    const int cur = step & 1;
    if (step < 7) {
      QKV_STAGE(cur ^ 1, (step + 1) * 64);
      asm volatile("s_waitcnt vmcnt(6)");   // 6 newest (next tile) may stay in flight
    } else {
      asm volatile("s_waitcnt vmcnt(0)");
    }
    __builtin_amdgcn_s_barrier();
#pragma unroll
    for (int kk = 0; kk < 2; ++kk) {
      bf16x8 af[2], bfr[4];
#pragma unroll
      for (int mi = 0; mi < 2; ++mi) {
        int row = wr * 32 + mi * 16 + li;
        int sw = ((kk * 4 + g) ^ (row & 7)) * 8;
        af[mi] = *(const bf16x8*)(&As[cur][0] + row * 64 + sw);
      }
#pragma unroll
      for (int ni = 0; ni < 4; ++ni) {
        int row = wc * 64 + ni * 16 + li;
        int sw = ((kk * 4 + g) ^ (row & 7)) * 8;
        bfr[ni] = *(const bf16x8*)(&Bs[cur][0] + row * 64 + sw);
      }
#pragma unroll
      for (int mi = 0; mi < 2; ++mi)
#pragma unroll
        for (int ni = 0; ni < 4; ++ni)
          acc[mi][ni] = __builtin_amdgcn_mfma_f32_16x16x32_bf16(af[mi], bfr[ni], acc[mi][ni], 0, 0, 0);
    }
    asm volatile("s_waitcnt lgkmcnt(0)");
    __builtin_amdgcn_sched_barrier(0);
    __builtin_amdgcn_s_barrier();
  }
#pragma unroll
  for (int ni = 0; ni < 4; ++ni) {
    int n = n0 + wc * 64 + ni * 16 + li;
    float bn = bias[n];
    int sel = n >> 9, c = n & 511, hh = c >> 6, d = c & 63;
    if (sel == 0) {        // Q: [bh][t][d], scaled
#pragma unroll
      for (int mi = 0; mi < 2; ++mi) {
#pragma unroll
        for (int r = 0; r < 4; ++r) {
          int m = m0 + wr * 32 + mi * 16 + g * 4 + r;
          int bq = m >> 11, t = m & 2047;
          Qo[((size_t)((bq * NHn + hh) * Tn + t)) * HDn + d] = f2bf((acc[mi][ni][r] + bn) * QSC);
        }
      }
    } else if (sel == 1) {  // K': tiled fragment layout
      int kc = d >> 4, khi = (d >> 3) & 1, kj = d & 7;
#pragma unroll
      for (int mi = 0; mi < 2; ++mi) {
#pragma unroll
        for (int r = 0; r < 4; ++r) {
          int m = m0 + wr * 32 + mi * 16 + g * 4 + r;
          int bq = m >> 11, t = m & 2047;
          size_t off = (size_t)(bq * NHn + hh) * 131072 + (size_t)(t >> 5) * 2048 +
                       kc * 512 + khi * 256 + (t & 31) * 8 + kj;
          Kp[off] = f2bf(acc[mi][ni][r] + bn);
        }
      }
    } else {                // V': tiled slot layout, 4 consecutive keys pack to 8B
      int dh = d >> 5, lqd = d & 31;
#pragma unroll
      for (int mi = 0; mi < 2; ++mi) {
        int mb = m0 + wr * 32 + mi * 16 + g * 4;
        int bq = mb >> 11, t0 = mb & 2047;
        size_t off = (size_t)(bq * NHn + hh) * 131072 + (size_t)(t0 >> 5) * 2048 +
                     dh * 1024 + ((t0 >> 4) & 1) * 512 + lqd * 16 +
                     ((t0 >> 2) & 1) * 8 + ((t0 >> 3) & 1) * 4;
        u32x2 ov;
        ov.x = cvtpk(acc[mi][ni][0] + bn, acc[mi][ni][1] + bn);
        ov.y = cvtpk(acc[mi][ni][2] + bn, acc[mi][ni][3] + bn);
        *(u32x2*)(Vp + off) = ov;
      }
    }
  }
}

// ---------- flash attention, block-causal, 32x32 swapped MFMA, 2-stage in-wave pipeline ----------
// 4 waves/block = 4 key-split segments of one 32-query tile; LDS combine.
// XCD-pinned: bh = (idx&7) | ((idx>>3)&1)<<3 keeps 2 bh per XCD (1MB K+V in local L2).
// Pipeline: per iter t: issue loads(K(t+1),V(t)) -> S(t) MFMAs -> PV(t-1) MFMAs -> softmax(t).
__global__ __launch_bounds__(256, 3) void attn(
    const u16* __restrict__ Q, const u16* __restrict__ Kp, const u16* __restrict__ Vp,
    u16* __restrict__ Y) {
  int idx = blockIdx.x;            // 1024
  int bh = (idx & 7) | (((idx >> 3) & 1) << 3);
  int qt = 63 - (idx >> 4);        // heavy first
  int b = bh >> 3, h = bh & 7;
  int qrow0 = qt << 5;
  int nkeys = ((qt >> 3) + 1) << 8;
  int qtr = nkeys >> 2;            // per-wave key range, multiple of 64
  int tid = threadIdx.x;
  int w = tid >> 6;                // segment
  int ktb = (w * qtr) >> 5;        // first 32-key tile of this segment
  int ntile = qtr >> 5;            // >= 2
  int lane = tid & 63;
  int lq = lane & 31;              // query col / K row / V d-row within tile
  int hi = lane >> 5;              // half select

  const u16* Qb = Q + ((size_t)(bh * Tn + qrow0)) * HDn;
  const u16* Kb = Kp + (size_t)bh * 131072;
  const u16* Vb = Vp + (size_t)bh * 131072;
  int kof = hi * 256 + lq * 8;     // K lane offset (u16)
  int vof = lq * 16 + hi * 8;      // V lane offset (u16)

  // Q^T B-frags: chunk c holds B[d=c*16+hi*8+j][q=lq]
  bf16x8 qf[4];
  {
    const u16* qp = Qb + (size_t)lq * HDn + hi * 8;
#pragma unroll
    for (int c = 0; c < 4; ++c) qf[c] = *(const bf16x8*)(qp + c * 16);
  }

  float mrun = -1e30f, lrun = 0.f;   // per-lane partials
  f32x16 oacc0 = {}, oacc1 = {};     // O^T d=0-31 / 32-63, col q=lq
  bf16x8 kc[4], knf[4], vc[4], vn[4];
  bf16x8 pfA, pfB;

#define KLD(dst, kt)                                                           \
  _Pragma("unroll")                                                            \
  for (int c = 0; c < 4; ++c)                                                  \
    dst[c] = *(const bf16x8*)(Kb + (size_t)(kt) * 2048 + c * 512 + kof);
#define VLD(dst, kt)                                                           \
  {                                                                            \
    const u16* vt_ = Vb + (size_t)(kt) * 2048 + vof;                           \
    _Pragma("unroll")                                                          \
    for (int c = 0; c < 4; ++c) dst[c] = *(const bf16x8*)(vt_ + c * 512);      \
  }
#define SQK()                                                                  \
  __builtin_amdgcn_s_setprio(1);                                               \
  _Pragma("unroll")                                                            \
  for (int c = 0; c < 4; ++c)                                                  \
    s = __builtin_amdgcn_mfma_f32_32x32x16_bf16(kc[c], qf[c], s, 0, 0, 0);     \
  __builtin_amdgcn_s_setprio(0);
#define PVB()                                                                  \
  __builtin_amdgcn_s_setprio(1);                                               \
  oacc0 = __builtin_amdgcn_mfma_f32_32x32x16_bf16(vc[0], pfA, oacc0, 0, 0, 0); \
  oacc0 = __builtin_amdgcn_mfma_f32_32x32x16_bf16(vc[1], pfB, oacc0, 0, 0, 0); \
  oacc1 = __builtin_amdgcn_mfma_f32_32x32x16_bf16(vc[2], pfA, oacc1, 0, 0, 0); \
  oacc1 = __builtin_amdgcn_mfma_f32_32x32x16_bf16(vc[3], pfB, oacc1, 0, 0, 0); \
  __builtin_amdgcn_s_setprio(0);
#define SMB()                                                                  \
  {                                                                            \
    float m0_ = fmaxf(fmaxf(fmaxf(fmaxf(s[0], s[1]), fmaxf(s[2], s[3])),       \
                            fmaxf(fmaxf(s[4], s[5]), fmaxf(s[6], s[7]))),      \
                      fmaxf(fmaxf(fmaxf(s[8], s[9]), fmaxf(s[10], s[11])),     \
                            fmaxf(fmaxf(s[12], s[13]), fmaxf(s[14], s[15])))); \
    float mall_ = fmaxf(m0_, __shfl_xor(m0_, 32));                             \
    if (!__all(mall_ <= mrun + 8.0f)) {                                        \
      float mnew_ = fmaxf(mrun, mall_);                                        \
      float fc_ = exp2f(mrun - mnew_);                                         \
      mrun = mnew_; lrun *= fc_;                                               \
      _Pragma("unroll")                                                        \
      for (int j = 0; j < 16; ++j) { oacc0[j] *= fc_; oacc1[j] *= fc_; }       \
    }                                                                          \
    float p[16];                                                               \
    _Pragma("unroll")                                                          \
    for (int j = 0; j < 16; ++j) p[j] = exp2f(s[j] - mrun);                    \
    lrun += (((p[0] + p[1]) + (p[2] + p[3])) + ((p[4] + p[5]) + (p[6] + p[7]))) + \
            (((p[8] + p[9]) + (p[10] + p[11])) + ((p[12] + p[13]) + (p[14] + p[15]))); \
    __attribute__((ext_vector_type(4))) int pa_ = {                            \
        (int)cvtpk(p[0], p[1]), (int)cvtpk(p[2], p[3]),                        \
        (int)cvtpk(p[4], p[5]), (int)cvtpk(p[6], p[7])};                       \
    __attribute__((ext_vector_type(4))) int pb_ = {                            \
        (int)cvtpk(p[8], p[9]), (int)cvtpk(p[10], p[11]),                      \
        (int)cvtpk(p[12], p[13]), (int)cvtpk(p[14], p[15])};                   \
    pfA = __builtin_bit_cast(bf16x8, pa_);                                     \
    pfB = __builtin_bit_cast(bf16x8, pb_);                                     \
  }

  // ---- peel t = 0 ----
  KLD(kc, ktb);
  VLD(vc, ktb);
  KLD(knf, ktb + 1);               // ntile >= 2 always
  {
    f32x16 s = {};
    SQK();
    SMB();
  }
#pragma unroll
  for (int c = 0; c < 4; ++c) kc[c] = knf[c];

  // ---- main loop t = 1 .. ntile-1 ----
  for (int t = 1; t < ntile; ++t) {
    int ktn = ktb + ((t + 1 < ntile) ? t + 1 : t);
    KLD(knf, ktn);                 // K(t+1)
    VLD(vn, ktb + t);              // V(t), used by PV(t) next iter
    f32x16 s = {};
    SQK();                         // S(t) with kc = K(t)
    PVB();                         // PV(t-1) with vc = V(t-1), pf = P(t-1)
    SMB();                         // softmax(t) -> pf; rescale lands after PV(t-1)
#pragma unroll
    for (int c = 0; c < 4; ++c) { kc[c] = knf[c]; vc[c] = vn[c]; }
  }
  // ---- epilogue: PV(ntile-1) ----
  PVB();

  // total l per query column (cross-half)
  lrun += __shfl_xor(lrun, 32);

  // partials -> LDS
  __shared__ float Ol[4][32][68];
  __shared__ float ml[2][4][32];
  {
    float* op = &Ol[w][lq][hi * 4];
#pragma unroll
    for (int a = 0; a < 4; ++a) {
      f32x4 v0 = {oacc0[4 * a], oacc0[4 * a + 1], oacc0[4 * a + 2], oacc0[4 * a + 3]};
      f32x4 v1 = {oacc1[4 * a], oacc1[4 * a + 1], oacc1[4 * a + 2], oacc1[4 * a + 3]};
      *(f32x4*)(op + a * 8) = v0;
      *(f32x4*)(op + 32 + a * 8) = v1;
    }
    if (lane < 32) { ml[0][w][lq] = mrun; ml[1][w][lq] = lrun; }
  }
  __syncthreads();

  // in-block combine of the 4 segments; write Y bf16 [b][t][c]
#pragma unroll
  for (int task = tid; task < 512; task += 256) {
    int q = task >> 4, quad = task & 15;
    float m0v = ml[0][0][q], m1v = ml[0][1][q], m2v = ml[0][2][q], m3v = ml[0][3][q];
    float mx = fmaxf(fmaxf(m0v, m1v), fmaxf(m2v, m3v));
    float w0 = exp2f(m0v - mx), w1 = exp2f(m1v - mx);
    float w2 = exp2f(m2v - mx), w3 = exp2f(m3v - mx);
    float l = ml[1][0][q] * w0 + ml[1][1][q] * w1 + ml[1][2][q] * w2 + ml[1][3][q] * w3;
    float inv = 1.0f / l;
    f32x4 o0 = *(const f32x4*)&Ol[0][q][quad * 4];
    f32x4 o1 = *(const f32x4*)&Ol[1][q][quad * 4];
    f32x4 o2 = *(const f32x4*)&Ol[2][q][quad * 4];
    f32x4 o3 = *(const f32x4*)&Ol[3][q][quad * 4];
    float y0 = (o0[0] * w0 + o1[0] * w1 + o2[0] * w2 + o3[0] * w3) * inv;
    float y1 = (o0[1] * w0 + o1[1] * w1 + o2[1] * w2 + o3[1] * w3) * inv;
    float y2 = (o0[2] * w0 + o1[2] * w1 + o2[2] * w2 + o3[2] * w3) * inv;
    float y3 = (o0[3] * w0 + o1[3] * w1 + o2[3] * w2 + o3[3] * w3) * inv;
    u32x2 yv;
    yv.x = cvtpk(y0, y1);
    yv.y = cvtpk(y2, y3);
    *(u32x2*)(Y + ((size_t)(b * Tn + qrow0 + q)) * CCn + h * HDn + quad * 4) = yv;
  }
}

// ---------- GEMM2: Y x WoT + bias -> out (v,b,c,h,w) f32, fused transpose; 2-phase staging ----------
__global__ __launch_bounds__(256, 4) void gemm_out(
    const u16* __restrict__ A, const u16* __restrict__ Bt, const float* __restrict__ bias,
    float* __restrict__ out) {
  const int nt = 8;
  int m0 = (blockIdx.x / nt) * 64;
  int n0 = (blockIdx.x % nt) * 64;
  __shared__ __align__(16) u16 As[2][64 * 64];
  __shared__ __align__(16) u16 Bs[2][64 * 64];
  int tid = threadIdx.x, lane = tid & 63, w = tid >> 6;
  int wr = w & 1, wc = w >> 1;
  int li = lane & 15, g = lane >> 4;
  int rsub = lane >> 3, slot = lane & 7;
  int srcslot = slot ^ rsub;
  f32x4 acc[2][2] = {};

#define OUT_STAGE(buf, kk0)                                                    \
  {                                                                            \
    _Pragma("unroll")                                                          \
    for (int i = 0; i < 2; ++i) {                                              \
      int ci = w * 2 + i;                                                      \
      int row = ci * 8 + rsub;                                                 \
      gload16(A + (size_t)(m0 + row) * Kn + (kk0) + srcslot * 8,               \
              (char*)&As[buf][0] + ci * 1024);                                 \
      gload16(Bt + (size_t)(n0 + row) * Kn + (kk0) + srcslot * 8,              \
              (char*)&Bs[buf][0] + ci * 1024);                                 \
    }                                                                          \
  }

  OUT_STAGE(0, 0);
#pragma unroll
  for (int step = 0; step < 8; ++step) {
    const int cur = step & 1;
    if (step < 7) {
      OUT_STAGE(cur ^ 1, (step + 1) * 64);
      asm volatile("s_waitcnt vmcnt(4)");
    } else {
      asm volatile("s_waitcnt vmcnt(0)");
    }
    __builtin_amdgcn_s_barrier();
#pragma unroll
    for (int kk = 0; kk < 2; ++kk) {
      bf16x8 af[2], bfr[2];
#pragma unroll
      for (int mi = 0; mi < 2; ++mi) {
        int row = wr * 32 + mi * 16 + li;
        int sw = ((kk * 4 + g) ^ (row & 7)) * 8;
        af[mi] = *(const bf16x8*)(&As[cur][0] + row * 64 + sw);
      }
#pragma unroll
      for (int ni = 0; ni < 2; ++ni) {
        int row = wc * 32 + ni * 16 + li;
        int sw = ((kk * 4 + g) ^ (row & 7)) * 8;
        bfr[ni] = *(const bf16x8*)(&Bs[cur][0] + row * 64 + sw);
      }
#pragma unroll
      for (int mi = 0; mi < 2; ++mi)
#pragma unroll
        for (int ni = 0; ni < 2; ++ni)
          acc[mi][ni] = __builtin_amdgcn_mfma_f32_16x16x32_bf16(af[mi], bfr[ni], acc[mi][ni], 0, 0, 0);
    }
    asm volatile("s_waitcnt lgkmcnt(0)");
    __builtin_amdgcn_sched_barrier(0);
    __builtin_amdgcn_s_barrier();
  }
  // epilogue: out[(v*2+b)*512 + n][hw], m = b*2048 + v*256 + hw; m0 64-aligned -> b,v fixed
  int b = m0 >> 11, v = (m0 >> 8) & 7, hw0 = m0 & 255;
  float* ob = out + (size_t)((v * 2 + b) * 512) * 256;
#pragma unroll
  for (int ni = 0; ni < 2; ++ni) {
    int n = n0 + wc * 32 + ni * 16 + li;
    float bn = bias[n];
#pragma unroll
    for (int mi = 0; mi < 2; ++mi) {
      int hw = hw0 + wr * 32 + mi * 16 + g * 4;
      f32x4 y;
#pragma unroll
      for (int r = 0; r < 4; ++r) y[r] = acc[mi][ni][r] + bn;
      *(f32x4*)(ob + (size_t)n * 256 + hw) = y;
    }
  }
}

extern "C" void kernel_launch(void* const* d_in, const int* in_sizes, int n_in,
                              void* d_out, int out_size, void* d_ws, size_t ws_size,
                              hipStream_t stream) {
  (void)in_sizes; (void)n_in; (void)out_size; (void)ws_size;
  const float* x    = (const float*)d_in[0];
  const float* Wqkv = (const float*)d_in[1];
  const float* bqkv = (const float*)d_in[2];
  const float* Wo   = (const float*)d_in[3];
  const float* bo   = (const float*)d_in[4];
  float* out = (float*)d_out;
  char* ws = (char*)d_ws;
  const size_t MB = 1ull << 20;
  u16*   Abf   = (u16*)(ws + 0);          // 4MB; reused as Y (bf16) after attn
  u16*   WqkvT = (u16*)(ws + 4 * MB);     // 1.5MB
  u16*   WoT   = (u16*)(ws + 5 * MB + 512 * 1024);  // 0.5MB
  u16*   Qb    = (u16*)(ws + 6 * MB);     // 4MB
  u16*   Kb    = (u16*)(ws + 10 * MB);    // 4MB (K' tiled)
  u16*   VTb   = (u16*)(ws + 14 * MB);    // 4MB (V' tiled)  -> peak 18MB

  prep<<<768, 256, 0, stream>>>(x, Wqkv, Wo, Abf, WqkvT, WoT);
  gemm_qkv<<<64 * 12, 256, 0, stream>>>(Abf, WqkvT, bqkv, Qb, Kb, VTb);
  attn<<<1024, 256, 0, stream>>>(Qb, Kb, VTb, Abf);
  gemm_out<<<64 * 8, 256, 0, stream>>>(Abf, WoT, bo, out);
}

// Round 18
// 57.621 us; speedup vs baseline: 1.0529x; 1.0016x over previous
//
#include <hip/hip_runtime.h>
#include <hip/hip_bf16.h>
#include <stdint.h>

#define VPn 8
#define BBn 2
#define CCn 512
#define NHn 8
#define HDn 64
#define Tn  2048
#define Mn  4096      // BBn*Tn
#define N1n 1536
#define Kn  512
#define QSC 0.180336880111120425f   // 0.125 * log2(e): softmax in exp2 domain

typedef __attribute__((ext_vector_type(8))) short bf16x8;
typedef __attribute__((ext_vector_type(4))) short s16x4;
typedef __attribute__((ext_vector_type(4))) float f32x4;
typedef __attribute__((ext_vector_type(16))) float f32x16;
typedef __attribute__((ext_vector_type(2))) unsigned int u32x2;
typedef unsigned short u16;
typedef unsigned int   u32;

__device__ __forceinline__ u16 f2bf(float f) {
  return __builtin_bit_cast(u16, __float2bfloat16(f));
}
// packed RNE f32x2 -> bf16x2 (same rounding as __float2bfloat16, 1 instr for 2 values)
__device__ __forceinline__ u32 cvtpk(float lo, float hi) {
  u32 r;
  asm("v_cvt_pk_bf16_f32 %0, %1, %2" : "=v"(r) : "v"(lo), "v"(hi));
  return r;
}
__device__ __forceinline__ void gload16(const void* g, void* l) {
  __builtin_amdgcn_global_load_lds(
      (const __attribute__((address_space(1))) u32*)g,
      (__attribute__((address_space(3))) u32*)l, 16, 0, 0);
}

// ---------- merged prologue: x transpose-convert + both W transposes ----------
__global__ __launch_bounds__(256) void prep(const float* __restrict__ x,
                                            const float* __restrict__ Wqkv,
                                            const float* __restrict__ Wo,
                                            u16* __restrict__ A,
                                            u16* __restrict__ WqkvT,
                                            u16* __restrict__ WoT) {
  int bi = blockIdx.x;   // 0..511 x ; 512..703 Wqkv ; 704..767 Wo
  __shared__ float t[64][65];
  int tid = threadIdx.x, col = tid & 63, r4 = tid >> 6;
  if (bi < 512) {
    int vb = bi >> 5;
    int ct = (bi >> 2) & 7;
    int ht = bi & 3;
    int v = vb >> 1, b = vb & 1;
    const float* src = x + ((size_t)vb * CCn + ct * 64) * 256 + ht * 64;
#pragma unroll
    for (int i = 0; i < 16; ++i) {
      int row = i * 4 + r4;                 // c within tile
      t[row][col] = src[row * 256 + col];   // col = hw within tile
    }
    __syncthreads();
    u16* dst = A + ((size_t)(b * Tn + v * 256 + ht * 64)) * Kn + ct * 64;
#pragma unroll
    for (int i = 0; i < 16; ++i) {
      int row = i * 4 + r4;                 // hw within tile
      dst[row * Kn + col] = f2bf(t[col][row]);
    }
  } else {
    const float* Win; u16* Wt; int Cc, rt, ct;
    if (bi < 704) { int k = bi - 512; Win = Wqkv; Wt = WqkvT; Cc = N1n; rt = k / 24; ct = k % 24; }
    else          { int k = bi - 704; Win = Wo;   Wt = WoT;   Cc = CCn; rt = k / 8;  ct = k % 8;  }
    const float* src = Win + (size_t)(rt * 64) * Cc + ct * 64;
#pragma unroll
    for (int i = 0; i < 16; ++i) {
      int row = i * 4 + r4;
      t[row][col] = src[row * Cc + col];
    }
    __syncthreads();
    u16* dst = Wt + (size_t)(ct * 64) * Kn + rt * 64;
#pragma unroll
    for (int i = 0; i < 16; ++i) {
      int row = i * 4 + r4;
      dst[row * Kn + col] = f2bf(t[col][row]);
    }
  }
}

// K' layout: [bh][kt][c][hi][lq][j]  (u16), flat = bh*131072 + kt*2048 + c*512 + hi*256 + lq*8 + j
// V' layout: [bh][kt][dh][ks][lq][pos] (u16), flat = bh*131072 + kt*2048 + dh*1024 + ks*512 + lq*16 + pos

// ---------- GEMM1: A x WqkvT -> Q (scaled), K', V'; 2-phase double-buffered staging ----------
__global__ __launch_bounds__(256, 3) void gemm_qkv(
    const u16* __restrict__ A, const u16* __restrict__ Bt, const float* __restrict__ bias,
    u16* __restrict__ Qo, u16* __restrict__ Kp, u16* __restrict__ Vp) {
  const int nt = N1n / 128;  // 12
  int m0 = (blockIdx.x / nt) * 64;
  int n0 = (blockIdx.x % nt) * 128;
  __shared__ __align__(16) u16 As[2][64 * 64];
  __shared__ __align__(16) u16 Bs[2][128 * 64];
  int tid = threadIdx.x, lane = tid & 63, w = tid >> 6;
  int wr = w & 1, wc = w >> 1;
  int li = lane & 15, g = lane >> 4;
  int rsub = lane >> 3, slot = lane & 7;
  int srcslot = slot ^ rsub;  // pre-swizzled global source (LDS dest stays linear)
  f32x4 acc[2][4] = {};

#define QKV_STAGE(buf, kk0)                                                    \
  {                                                                            \
    _Pragma("unroll")                                                          \
    for (int i = 0; i < 2; ++i) {                                              \
      int ci = w * 2 + i;                                                      \
      int row = ci * 8 + rsub;                                                 \
      gload16(A + (size_t)(m0 + row) * Kn + (kk0) + srcslot * 8,               \
              (char*)&As[buf][0] + ci * 1024);                                 \
    }                                                                          \
    _Pragma("unroll")                                                          \
    for (int i = 0; i < 4; ++i) {                                              \
      int ci = w * 4 + i;                                                      \
      int row = ci * 8 + rsub;                                                 \
      gload16(Bt + (size_t)(n0 + row) * Kn + (kk0) + srcslot * 8,              \
              (char*)&Bs[buf][0] + ci * 1024);                                 \
    }                                                                          \
  }

  QKV_STAGE(0, 0);
#pragma unroll
  for (int step = 0; step < 8; ++step) {
    const int cur = step & 1;
    if (step < 7) {
      QKV_STAGE(cur ^ 1, (step + 1) * 64);
      asm volatile("s_waitcnt vmcnt(6)");   // 6 newest (next tile) may stay in flight
    } else {
      asm volatile("s_waitcnt vmcnt(0)");
    }
    __builtin_amdgcn_s_barrier();
#pragma unroll
    for (int kk = 0; kk < 2; ++kk) {
      bf16x8 af[2], bfr[4];
#pragma unroll
      for (int mi = 0; mi < 2; ++mi) {
        int row = wr * 32 + mi * 16 + li;
        int sw = ((kk * 4 + g) ^ (row & 7)) * 8;
        af[mi] = *(const bf16x8*)(&As[cur][0] + row * 64 + sw);
      }
#pragma unroll
      for (int ni = 0; ni < 4; ++ni) {
        int row = wc * 64 + ni * 16 + li;
        int sw = ((kk * 4 + g) ^ (row & 7)) * 8;
        bfr[ni] = *(const bf16x8*)(&Bs[cur][0] + row * 64 + sw);
      }
#pragma unroll
      for (int mi = 0; mi < 2; ++mi)
#pragma unroll
        for (int ni = 0; ni < 4; ++ni)
          acc[mi][ni] = __builtin_amdgcn_mfma_f32_16x16x32_bf16(af[mi], bfr[ni], acc[mi][ni], 0, 0, 0);
    }
    asm volatile("s_waitcnt lgkmcnt(0)");
    __builtin_amdgcn_sched_barrier(0);
    __builtin_amdgcn_s_barrier();
  }
#pragma unroll
  for (int ni = 0; ni < 4; ++ni) {
    int n = n0 + wc * 64 + ni * 16 + li;
    float bn = bias[n];
    int sel = n >> 9, c = n & 511, hh = c >> 6, d = c & 63;
    if (sel == 0) {        // Q: [bh][t][d], scaled
#pragma unroll
      for (int mi = 0; mi < 2; ++mi) {
#pragma unroll
        for (int r = 0; r < 4; ++r) {
          int m = m0 + wr * 32 + mi * 16 + g * 4 + r;
          int bq = m >> 11, t = m & 2047;
          Qo[((size_t)((bq * NHn + hh) * Tn + t)) * HDn + d] = f2bf((acc[mi][ni][r] + bn) * QSC);
        }
      }
    } else if (sel == 1) {  // K': tiled fragment layout
      int kc = d >> 4, khi = (d >> 3) & 1, kj = d & 7;
#pragma unroll
      for (int mi = 0; mi < 2; ++mi) {
#pragma unroll
        for (int r = 0; r < 4; ++r) {
          int m = m0 + wr * 32 + mi * 16 + g * 4 + r;
          int bq = m >> 11, t = m & 2047;
          size_t off = (size_t)(bq * NHn + hh) * 131072 + (size_t)(t >> 5) * 2048 +
                       kc * 512 + khi * 256 + (t & 31) * 8 + kj;
          Kp[off] = f2bf(acc[mi][ni][r] + bn);
        }
      }
    } else {                // V': tiled slot layout, 4 consecutive keys pack to 8B
      int dh = d >> 5, lqd = d & 31;
#pragma unroll
      for (int mi = 0; mi < 2; ++mi) {
        int mb = m0 + wr * 32 + mi * 16 + g * 4;
        int bq = mb >> 11, t0 = mb & 2047;
        size_t off = (size_t)(bq * NHn + hh) * 131072 + (size_t)(t0 >> 5) * 2048 +
                     dh * 1024 + ((t0 >> 4) & 1) * 512 + lqd * 16 +
                     ((t0 >> 2) & 1) * 8 + ((t0 >> 3) & 1) * 4;
        u32x2 ov;
        ov.x = cvtpk(acc[mi][ni][0] + bn, acc[mi][ni][1] + bn);
        ov.y = cvtpk(acc[mi][ni][2] + bn, acc[mi][ni][3] + bn);
        *(u32x2*)(Vp + off) = ov;
      }
    }
  }
}

// ---------- flash attention, block-causal, 32x32 swapped MFMA, 2-stage in-wave pipeline ----------
// 4 waves/block = 4 key-split segments of one 32-query tile; LDS combine.
// XCD-pinned: bh = (idx&7) | ((idx>>3)&1)<<3 keeps 2 bh per XCD (1MB K+V in local L2).
// Pipeline: per iter t: issue loads(K(t+1),V(t)) -> S(t) MFMAs -> PV(t-1) MFMAs -> softmax(t).
__global__ __launch_bounds__(256, 3) void attn(
    const u16* __restrict__ Q, const u16* __restrict__ Kp, const u16* __restrict__ Vp,
    u16* __restrict__ Y) {
  int idx = blockIdx.x;            // 1024
  int bh = (idx & 7) | (((idx >> 3) & 1) << 3);
  int qt = 63 - (idx >> 4);        // heavy first
  int b = bh >> 3, h = bh & 7;
  int qrow0 = qt << 5;
  int nkeys = ((qt >> 3) + 1) << 8;
  int qtr = nkeys >> 2;            // per-wave key range, multiple of 64
  int tid = threadIdx.x;
  int w = tid >> 6;                // segment
  int ktb = (w * qtr) >> 5;        // first 32-key tile of this segment
  int ntile = qtr >> 5;            // >= 2
  int lane = tid & 63;
  int lq = lane & 31;              // query col / K row / V d-row within tile
  int hi = lane >> 5;              // half select

  const u16* Qb = Q + ((size_t)(bh * Tn + qrow0)) * HDn;
  const u16* Kb = Kp + (size_t)bh * 131072;
  const u16* Vb = Vp + (size_t)bh * 131072;
  int kof = hi * 256 + lq * 8;     // K lane offset (u16)
  int vof = lq * 16 + hi * 8;      // V lane offset (u16)

  // Q^T B-frags: chunk c holds B[d=c*16+hi*8+j][q=lq]
  bf16x8 qf[4];
  {
    const u16* qp = Qb + (size_t)lq * HDn + hi * 8;
#pragma unroll
    for (int c = 0; c < 4; ++c) qf[c] = *(const bf16x8*)(qp + c * 16);
  }

  float mrun = -1e30f, lrun = 0.f;   // per-lane partials
  f32x16 oacc0 = {}, oacc1 = {};     // O^T d=0-31 / 32-63, col q=lq
  bf16x8 kc[4], knf[4], vc[4], vn[4];
  bf16x8 pfA, pfB;

#define KLD(dst, kt)                                                           \
  _Pragma("unroll")                                                            \
  for (int c = 0; c < 4; ++c)                                                  \
    dst[c] = *(const bf16x8*)(Kb + (size_t)(kt) * 2048 + c * 512 + kof);
#define VLD(dst, kt)                                                           \
  {                                                                            \
    const u16* vt_ = Vb + (size_t)(kt) * 2048 + vof;                           \
    _Pragma("unroll")                                                          \
    for (int c = 0; c < 4; ++c) dst[c] = *(const bf16x8*)(vt_ + c * 512);      \
  }
#define SQK()                                                                  \
  __builtin_amdgcn_s_setprio(1);                                               \
  _Pragma("unroll")                                                            \
  for (int c = 0; c < 4; ++c)                                                  \
    s = __builtin_amdgcn_mfma_f32_32x32x16_bf16(kc[c], qf[c], s, 0, 0, 0);     \
  __builtin_amdgcn_s_setprio(0);
#define PVB()                                                                  \
  __builtin_amdgcn_s_setprio(1);                                               \
  oacc0 = __builtin_amdgcn_mfma_f32_32x32x16_bf16(vc[0], pfA, oacc0, 0, 0, 0); \
  oacc0 = __builtin_amdgcn_mfma_f32_32x32x16_bf16(vc[1], pfB, oacc0, 0, 0, 0); \
  oacc1 = __builtin_amdgcn_mfma_f32_32x32x16_bf16(vc[2], pfA, oacc1, 0, 0, 0); \
  oacc1 = __builtin_amdgcn_mfma_f32_32x32x16_bf16(vc[3], pfB, oacc1, 0, 0, 0); \
  __builtin_amdgcn_s_setprio(0);
#define SMB()                                                                  \
  {                                                                            \
    float m0_ = fmaxf(fmaxf(fmaxf(fmaxf(s[0], s[1]), fmaxf(s[2], s[3])),       \
                            fmaxf(fmaxf(s[4], s[5]), fmaxf(s[6], s[7]))),      \
                      fmaxf(fmaxf(fmaxf(s[8], s[9]), fmaxf(s[10], s[11])),     \
                            fmaxf(fmaxf(s[12], s[13]), fmaxf(s[14], s[15])))); \
    float mall_ = fmaxf(m0_, __shfl_xor(m0_, 32));                             \
    if (!__all(mall_ <= mrun + 8.0f)) {                                        \
      float mnew_ = fmaxf(mrun, mall_);                                        \
      float fc_ = exp2f(mrun - mnew_);                                         \
      mrun = mnew_; lrun *= fc_;                                               \
      _Pragma("unroll")                                                        \
      for (int j = 0; j < 16; ++j) { oacc0[j] *= fc_; oacc1[j] *= fc_; }       \
    }                                                                          \
    float p[16];                                                               \
    _Pragma("unroll")                                                          \
    for (int j = 0; j < 16; ++j) p[j] = exp2f(s[j] - mrun);                    \
    lrun += (((p[0] + p[1]) + (p[2] + p[3])) + ((p[4] + p[5]) + (p[6] + p[7]))) + \
            (((p[8] + p[9]) + (p[10] + p[11])) + ((p[12] + p[13]) + (p[14] + p[15]))); \
    __attribute__((ext_vector_type(4))) int pa_ = {                            \
        (int)cvtpk(p[0], p[1]), (int)cvtpk(p[2], p[3]),                        \
        (int)cvtpk(p[4], p[5]), (int)cvtpk(p[6], p[7])};                       \
    __attribute__((ext_vector_type(4))) int pb_ = {                            \
        (int)cvtpk(p[8], p[9]), (int)cvtpk(p[10], p[11]),                      \
        (int)cvtpk(p[12], p[13]), (int)cvtpk(p[14], p[15])};                   \
    pfA = __builtin_bit_cast(bf16x8, pa_);                                     \
    pfB = __builtin_bit_cast(bf16x8, pb_);                                     \
  }

  // ---- peel t = 0 ----
  KLD(kc, ktb);
  VLD(vc, ktb);
  KLD(knf, ktb + 1);               // ntile >= 2 always
  {
    f32x16 s = {};
    SQK();
    SMB();
  }
#pragma unroll
  for (int c = 0; c < 4; ++c) kc[c] = knf[c];

  // ---- main loop t = 1 .. ntile-1 ----
  for (int t = 1; t < ntile; ++t) {
    int ktn = ktb + ((t + 1 < ntile) ? t + 1 : t);
    KLD(knf, ktn);                 // K(t+1)
    VLD(vn, ktb + t);              // V(t), used by PV(t) next iter
    f32x16 s = {};
    SQK();                         // S(t) with kc = K(t)
    PVB();                         // PV(t-1) with vc = V(t-1), pf = P(t-1)
    SMB();                         // softmax(t) -> pf; rescale lands after PV(t-1)
#pragma unroll
    for (int c = 0; c < 4; ++c) { kc[c] = knf[c]; vc[c] = vn[c]; }
  }
  // ---- epilogue: PV(ntile-1) ----
  PVB();

  // total l per query column (cross-half)
  lrun += __shfl_xor(lrun, 32);

  // partials -> LDS
  __shared__ float Ol[4][32][68];
  __shared__ float ml[2][4][32];
  {
    float* op = &Ol[w][lq][hi * 4];
#pragma unroll
    for (int a = 0; a < 4; ++a) {
      f32x4 v0 = {oacc0[4 * a], oacc0[4 * a + 1], oacc0[4 * a + 2], oacc0[4 * a + 3]};
      f32x4 v1 = {oacc1[4 * a], oacc1[4 * a + 1], oacc1[4 * a + 2], oacc1[4 * a + 3]};
      *(f32x4*)(op + a * 8) = v0;
      *(f32x4*)(op + 32 + a * 8) = v1;
    }
    if (lane < 32) { ml[0][w][lq] = mrun; ml[1][w][lq] = lrun; }
  }
  __syncthreads();

  // in-block combine of the 4 segments; write Y bf16 [b][t][c]
#pragma unroll
  for (int task = tid; task < 512; task += 256) {
    int q = task >> 4, quad = task & 15;
    float m0v = ml[0][0][q], m1v = ml[0][1][q], m2v = ml[0][2][q], m3v = ml[0][3][q];
    float mx = fmaxf(fmaxf(m0v, m1v), fmaxf(m2v, m3v));
    float w0 = exp2f(m0v - mx), w1 = exp2f(m1v - mx);
    float w2 = exp2f(m2v - mx), w3 = exp2f(m3v - mx);
    float l = ml[1][0][q] * w0 + ml[1][1][q] * w1 + ml[1][2][q] * w2 + ml[1][3][q] * w3;
    float inv = 1.0f / l;
    f32x4 o0 = *(const f32x4*)&Ol[0][q][quad * 4];
    f32x4 o1 = *(const f32x4*)&Ol[1][q][quad * 4];
    f32x4 o2 = *(const f32x4*)&Ol[2][q][quad * 4];
    f32x4 o3 = *(const f32x4*)&Ol[3][q][quad * 4];
    float y0 = (o0[0] * w0 + o1[0] * w1 + o2[0] * w2 + o3[0] * w3) * inv;
    float y1 = (o0[1] * w0 + o1[1] * w1 + o2[1] * w2 + o3[1] * w3) * inv;
    float y2 = (o0[2] * w0 + o1[2] * w1 + o2[2] * w2 + o3[2] * w3) * inv;
    float y3 = (o0[3] * w0 + o1[3] * w1 + o2[3] * w2 + o3[3] * w3) * inv;
    u32x2 yv;
    yv.x = cvtpk(y0, y1);
    yv.y = cvtpk(y2, y3);
    *(u32x2*)(Y + ((size_t)(b * Tn + qrow0 + q)) * CCn + h * HDn + quad * 4) = yv;
  }
}

// ---------- GEMM2: Y x WoT + bias -> out (v,b,c,h,w) f32, fused transpose; 2-phase staging ----------
__global__ __launch_bounds__(256, 4) void gemm_out(
    const u16* __restrict__ A, const u16* __restrict__ Bt, const float* __restrict__ bias,
    float* __restrict__ out) {
  const int nt = 8;
  int m0 = (blockIdx.x / nt) * 64;
  int n0 = (blockIdx.x % nt) * 64;
  __shared__ __align__(16) u16 As[2][64 * 64];
  __shared__ __align__(16) u16 Bs[2][64 * 64];
  int tid = threadIdx.x, lane = tid & 63, w = tid >> 6;
  int wr = w & 1, wc = w >> 1;
  int li = lane & 15, g = lane >> 4;
  int rsub = lane >> 3, slot = lane & 7;
  int srcslot = slot ^ rsub;
  f32x4 acc[2][2] = {};

#define OUT_STAGE(buf, kk0)                                                    \
  {                                                                            \
    _Pragma("unroll")                                                          \
    for (int i = 0; i < 2; ++i) {                                              \
      int ci = w * 2 + i;                                                      \
      int row = ci * 8 + rsub;                                                 \
      gload16(A + (size_t)(m0 + row) * Kn + (kk0) + srcslot * 8,               \
              (char*)&As[buf][0] + ci * 1024);                                 \
      gload16(Bt + (size_t)(n0 + row) * Kn + (kk0) + srcslot * 8,              \
              (char*)&Bs[buf][0] + ci * 1024);                                 \
    }                                                                          \
  }

  OUT_STAGE(0, 0);
#pragma unroll
  for (int step = 0; step < 8; ++step) {
    const int cur = step & 1;
    if (step < 7) {
      OUT_STAGE(cur ^ 1, (step + 1) * 64);
      asm volatile("s_waitcnt vmcnt(4)");
    } else {
      asm volatile("s_waitcnt vmcnt(0)");
    }
    __builtin_amdgcn_s_barrier();
#pragma unroll
    for (int kk = 0; kk < 2; ++kk) {
      bf16x8 af[2], bfr[2];
#pragma unroll
      for (int mi = 0; mi < 2; ++mi) {
        int row = wr * 32 + mi * 16 + li;
        int sw = ((kk * 4 + g) ^ (row & 7)) * 8;
        af[mi] = *(const bf16x8*)(&As[cur][0] + row * 64 + sw);
      }
#pragma unroll
      for (int ni = 0; ni < 2; ++ni) {
        int row = wc * 32 + ni * 16 + li;
        int sw = ((kk * 4 + g) ^ (row & 7)) * 8;
        bfr[ni] = *(const bf16x8*)(&Bs[cur][0] + row * 64 + sw);
      }
#pragma unroll
      for (int mi = 0; mi < 2; ++mi)
#pragma unroll
        for (int ni = 0; ni < 2; ++ni)
          acc[mi][ni] = __builtin_amdgcn_mfma_f32_16x16x32_bf16(af[mi], bfr[ni], acc[mi][ni], 0, 0, 0);
    }
    asm volatile("s_waitcnt lgkmcnt(0)");
    __builtin_amdgcn_sched_barrier(0);
    __builtin_amdgcn_s_barrier();
  }
  // epilogue: out[(v*2+b)*512 + n][hw], m = b*2048 + v*256 + hw; m0 64-aligned -> b,v fixed
  int b = m0 >> 11, v = (m0 >> 8) & 7, hw0 = m0 & 255;
  float* ob = out + (size_t)((v * 2 + b) * 512) * 256;
#pragma unroll
  for (int ni = 0; ni < 2; ++ni) {
    int n = n0 + wc * 32 + ni * 16 + li;
    float bn = bias[n];
#pragma unroll
    for (int mi = 0; mi < 2; ++mi) {
      int hw = hw0 + wr * 32 + mi * 16 + g * 4;
      f32x4 y;
#pragma unroll
      for (int r = 0; r < 4; ++r) y[r] = acc[mi][ni][r] + bn;
      *(f32x4*)(ob + (size_t)n * 256 + hw) = y;
    }
  }
}

extern "C" void kernel_launch(void* const* d_in, const int* in_sizes, int n_in,
                              void* d_out, int out_size, void* d_ws, size_t ws_size,
                              hipStream_t stream) {
  (void)in_sizes; (void)n_in; (void)out_size; (void)ws_size;
  const float* x    = (const float*)d_in[0];
  const float* Wqkv = (const float*)d_in[1];
  const float* bqkv = (const float*)d_in[2];
  const float* Wo   = (const float*)d_in[3];
  const float* bo   = (const float*)d_in[4];
  float* out = (float*)d_out;
  char* ws = (char*)d_ws;
  const size_t MB = 1ull << 20;
  u16*   Abf   = (u16*)(ws + 0);          // 4MB; reused as Y (bf16) after attn
  u16*   WqkvT = (u16*)(ws + 4 * MB);     // 1.5MB
  u16*   WoT   = (u16*)(ws + 5 * MB + 512 * 1024);  // 0.5MB
  u16*   Qb    = (u16*)(ws + 6 * MB);     // 4MB
  u16*   Kb    = (u16*)(ws + 10 * MB);    // 4MB (K' tiled)
  u16*   VTb   = (u16*)(ws + 14 * MB);    // 4MB (V' tiled)  -> peak 18MB

  prep<<<768, 256, 0, stream>>>(x, Wqkv, Wo, Abf, WqkvT, WoT);
  gemm_qkv<<<64 * 12, 256, 0, stream>>>(Abf, WqkvT, bqkv, Qb, Kb, VTb);
  attn<<<1024, 256, 0, stream>>>(Qb, Kb, VTb, Abf);
  gemm_out<<<64 * 8, 256, 0, stream>>>(Abf, WoT, bo, out);
}